// Round 1
// baseline (510.442 us; speedup 1.0000x reference)
//
#include <hip/hip_runtime.h>
#include <hip/hip_bf16.h>

typedef __bf16 bf16_t;
typedef __bf16 bf16x8_t __attribute__((ext_vector_type(8)));
typedef float f32x4_t __attribute__((ext_vector_type(4)));

static constexpr int B_ = 2, S_ = 2048, D_ = 512, H_ = 8, DK_ = 64, DFF_ = 2048;
static constexpr int M_ = B_ * S_;  // 4096 tokens

// ---------------------------------------------------------------------------
// LayerNorm (torch style: a*(x-mean)/(std+eps)+b, std unbiased ddof=1)
// fp32 in -> bf16 out. One wave per row (512 cols), 4 rows per block.
// ---------------------------------------------------------------------------
__global__ __launch_bounds__(256) void ln_kernel(const float* __restrict__ x,
                                                 const float* __restrict__ ga,
                                                 const float* __restrict__ gb,
                                                 bf16_t* __restrict__ out) {
  const int row = blockIdx.x * 4 + (threadIdx.x >> 6);
  const int lane = threadIdx.x & 63;
  const float4* xr = (const float4*)(x + (long)row * D_);
  float4 v0 = xr[lane * 2];
  float4 v1 = xr[lane * 2 + 1];
  float s = v0.x + v0.y + v0.z + v0.w + v1.x + v1.y + v1.z + v1.w;
  float ss = v0.x * v0.x + v0.y * v0.y + v0.z * v0.z + v0.w * v0.w +
             v1.x * v1.x + v1.y * v1.y + v1.z * v1.z + v1.w * v1.w;
#pragma unroll
  for (int m = 1; m < 64; m <<= 1) {
    s += __shfl_xor(s, m);
    ss += __shfl_xor(ss, m);
  }
  const float mean = s * (1.0f / 512.0f);
  float var = (ss - 512.0f * mean * mean) * (1.0f / 511.0f);
  var = fmaxf(var, 0.0f);
  const float sc = ga[0] / (sqrtf(var) + 1e-6f);
  const float sh = gb[0] - mean * sc;
  alignas(16) bf16_t y[8];
  y[0] = (bf16_t)(v0.x * sc + sh);
  y[1] = (bf16_t)(v0.y * sc + sh);
  y[2] = (bf16_t)(v0.z * sc + sh);
  y[3] = (bf16_t)(v0.w * sc + sh);
  y[4] = (bf16_t)(v1.x * sc + sh);
  y[5] = (bf16_t)(v1.y * sc + sh);
  y[6] = (bf16_t)(v1.z * sc + sh);
  y[7] = (bf16_t)(v1.w * sc + sh);
  ((uint4*)(out + (long)row * D_))[lane] = *(uint4*)y;
}

// ---------------------------------------------------------------------------
// fp32 -> bf16 convert (encoder_output)
// ---------------------------------------------------------------------------
__global__ __launch_bounds__(256) void cvt_bf16(const float* __restrict__ x,
                                                bf16_t* __restrict__ y) {
  const long i = ((long)blockIdx.x * 256 + threadIdx.x) * 8;
  float4 a = *(const float4*)(x + i);
  float4 b = *(const float4*)(x + i + 4);
  alignas(16) bf16_t t[8];
  t[0] = (bf16_t)a.x; t[1] = (bf16_t)a.y; t[2] = (bf16_t)a.z; t[3] = (bf16_t)a.w;
  t[4] = (bf16_t)b.x; t[5] = (bf16_t)b.y; t[6] = (bf16_t)b.z; t[7] = (bf16_t)b.w;
  *(uint4*)(y + i) = *(uint4*)t;
}

// ---------------------------------------------------------------------------
// Weight convert+transpose: W[K][N] fp32 -> Wt[N][K] bf16. 64x64 tiles.
// ---------------------------------------------------------------------------
__global__ __launch_bounds__(256) void wtrans(const float* __restrict__ W,
                                              bf16_t* __restrict__ Wt, int K, int N) {
  constexpr int LDT = 65;
  __shared__ float T[64 * LDT];
  const int tid = threadIdx.x;
  const int k0 = blockIdx.x * 64, n0 = blockIdx.y * 64;
#pragma unroll
  for (int p = 0; p < 4; ++p) {
    int e = p * 1024 + tid * 4;
    int kr = e >> 6, nc = e & 63;
    float4 f = *(const float4*)(W + (long)(k0 + kr) * N + n0 + nc);
    T[kr * LDT + nc + 0] = f.x;
    T[kr * LDT + nc + 1] = f.y;
    T[kr * LDT + nc + 2] = f.z;
    T[kr * LDT + nc + 3] = f.w;
  }
  __syncthreads();
#pragma unroll
  for (int p = 0; p < 4; ++p) {
    int e = p * 1024 + tid * 4;
    int nr = e >> 6, kc = e & 63;
    alignas(8) bf16_t t[4];
#pragma unroll
    for (int j = 0; j < 4; ++j) t[j] = (bf16_t)T[(kc + j) * LDT + nr];
    *(uint2*)(Wt + (long)(n0 + nr) * K + k0 + kc) = *(uint2*)t;
  }
}

// ---------------------------------------------------------------------------
// V transpose for attention: v[token][512] -> vt[bh][64 d][2048 s] (bf16)
// ---------------------------------------------------------------------------
__global__ __launch_bounds__(256) void vtrans(const bf16_t* __restrict__ v,
                                              bf16_t* __restrict__ vt) {
  constexpr int LDT = 66;
  __shared__ bf16_t T[64 * LDT];  // [d][s_local]
  const int tid = threadIdx.x;
  const int bh = blockIdx.y, b = bh >> 3, h = bh & 7;
  const int s0 = blockIdx.x * 64;
#pragma unroll
  for (int p = 0; p < 2; ++p) {
    int e = p * 2048 + tid * 8;
    int sr = e >> 6, c = e & 63;
    uint4 u = *(const uint4*)(v + (long)(b * S_ + s0 + sr) * D_ + h * DK_ + c);
    bf16_t* pv = (bf16_t*)&u;
#pragma unroll
    for (int j = 0; j < 8; ++j) T[(c + j) * LDT + sr] = pv[j];
  }
  __syncthreads();
#pragma unroll
  for (int p = 0; p < 2; ++p) {
    int e = p * 2048 + tid * 8;
    int d = e >> 6, sc = e & 63;
    alignas(16) bf16_t t[8];
#pragma unroll
    for (int j = 0; j < 8; ++j) t[j] = T[d * LDT + sc + j];
    *(uint4*)(vt + ((long)bh * DK_ + d) * S_ + s0 + sc) = *(uint4*)t;
  }
}

// ---------------------------------------------------------------------------
// GEMM: out = act(A @ Wt^T + bias) (+res). A[M][K] bf16, Wt[N][K] bf16.
// BM=128, BK=32, BN in {128,64}. 256 threads = 4 waves.
// MODE 0: bf16 out. 1: bf16 relu out. 2: fp32 out + fp32 residual.
// LDS stride 40 elems: 80B rows keep ds_read_b128 16B-aligned and spread the
// 8-lane read phases over all 32 banks (stride 32 would 4-way conflict).
// ---------------------------------------------------------------------------
struct GArg {
  const bf16_t* A;
  const bf16_t* Wt;
  const float* bias;
  const float* res;
  void* out;
};

template <int BN, int MODE>
__global__ __launch_bounds__(256, 2) void gemm_bt(GArg g0, GArg g1, GArg g2,
                                                  int M, int N, int K) {
  constexpr int WAVES_N = BN / 64;
  constexpr int WAVES_M = 4 / WAVES_N;
  constexpr int WM = 128 / WAVES_M;
  constexpr int AI = WM / 16;
  constexpr int LDA = 40;
  __shared__ bf16_t As[128 * LDA];
  __shared__ bf16_t Bs[BN * LDA];
  GArg g = (blockIdx.z == 0) ? g0 : (blockIdx.z == 1) ? g1 : g2;
  const int tid = threadIdx.x;
  const int wave = tid >> 6, lane = tid & 63, quad = lane >> 4, l15 = lane & 15;
  const long m0 = (long)blockIdx.x * 128;
  const long n0 = (long)blockIdx.y * BN;
  const int wm = (wave / WAVES_N) * WM;
  const int wn = (wave % WAVES_N) * 64;

  const int ar = tid >> 2;         // 0..63
  const int ac = (tid & 3) * 8;    // 0,8,16,24
  const bf16_t* Ag = g.A + (m0 + ar) * (long)K + ac;
  const bf16_t* Bg = g.Wt + (n0 + ar) * (long)K + ac;

  f32x4_t acc[AI][4];
#pragma unroll
  for (int i = 0; i < AI; ++i)
#pragma unroll
    for (int j = 0; j < 4; ++j) acc[i][j] = (f32x4_t){0.f, 0.f, 0.f, 0.f};

  for (int k0 = 0; k0 < K; k0 += 32) {
    uint4 a0 = *(const uint4*)(Ag + k0);
    uint4 a1 = *(const uint4*)(Ag + 64 * (long)K + k0);
    uint4 b0 = *(const uint4*)(Bg + k0);
    uint4 b1;
    if constexpr (BN == 128) b1 = *(const uint4*)(Bg + 64 * (long)K + k0);
    __syncthreads();
    *(uint4*)&As[ar * LDA + ac] = a0;
    *(uint4*)&As[(ar + 64) * LDA + ac] = a1;
    *(uint4*)&Bs[ar * LDA + ac] = b0;
    if constexpr (BN == 128) *(uint4*)&Bs[(ar + 64) * LDA + ac] = b1;
    __syncthreads();
    bf16x8_t af[AI], bfr[4];
#pragma unroll
    for (int i = 0; i < AI; ++i)
      af[i] = *(const bf16x8_t*)&As[(wm + i * 16 + l15) * LDA + quad * 8];
#pragma unroll
    for (int j = 0; j < 4; ++j)
      bfr[j] = *(const bf16x8_t*)&Bs[(wn + j * 16 + l15) * LDA + quad * 8];
#pragma unroll
    for (int i = 0; i < AI; ++i)
#pragma unroll
      for (int j = 0; j < 4; ++j)
        acc[i][j] = __builtin_amdgcn_mfma_f32_16x16x32_bf16(af[i], bfr[j], acc[i][j], 0, 0, 0);
  }

#pragma unroll
  for (int i = 0; i < AI; ++i) {
#pragma unroll
    for (int j = 0; j < 4; ++j) {
      const long col = n0 + wn + j * 16 + l15;
      const float bv = g.bias[col];
#pragma unroll
      for (int r = 0; r < 4; ++r) {
        const long row = m0 + wm + i * 16 + quad * 4 + r;
        float v = acc[i][j][r] + bv;
        if constexpr (MODE == 1) v = fmaxf(v, 0.f);
        if constexpr (MODE == 2) {
          ((float*)g.out)[row * N + col] = v + g.res[row * N + col];
        } else {
          ((bf16_t*)g.out)[row * N + col] = (bf16_t)v;
        }
      }
    }
  }
}

// ---------------------------------------------------------------------------
// Flash attention. Q,K: [token][512] bf16 (head h at col h*64). Vt: [bh][d][s].
// 64 q rows / block (4 waves x 16), K-tile 64. Online softmax in fp32.
// ---------------------------------------------------------------------------
template <bool CAUSAL>
__global__ __launch_bounds__(256, 2) void flash_attn(const bf16_t* __restrict__ Q,
                                                     const bf16_t* __restrict__ Kg,
                                                     const bf16_t* __restrict__ Vt,
                                                     bf16_t* __restrict__ O) {
  constexpr int LDK = 72;  // 144B rows: 16B-aligned, conflict-spread
  __shared__ bf16_t Ks[64 * LDK];       // [kk][d]
  __shared__ bf16_t Vs[64 * LDK];       // [d][kk]
  __shared__ bf16_t Ps[4][16 * LDK];    // per-wave P [q][kk]
  const int tid = threadIdx.x, wave = tid >> 6, lane = tid & 63;
  const int quad = lane >> 4, l15 = lane & 15;
  const int bh = blockIdx.y, b = bh >> 3, h = bh & 7;
  const int q0 = blockIdx.x * 64;
  const long base = ((long)b * S_) * D_ + (long)h * DK_;
  const long vtbase = (long)bh * DK_ * S_;

  const int qrow = q0 + wave * 16 + l15;  // A-operand row (m = lane&15)
  bf16x8_t qf[2];
  qf[0] = *(const bf16x8_t*)(Q + base + (long)qrow * D_ + quad * 8);
  qf[1] = *(const bf16x8_t*)(Q + base + (long)qrow * D_ + 32 + quad * 8);

  float mi[4], li[4];
  f32x4_t o[4];
#pragma unroll
  for (int r = 0; r < 4; ++r) { mi[r] = -1e30f; li[r] = 0.f; }
#pragma unroll
  for (int d = 0; d < 4; ++d) o[d] = (f32x4_t){0.f, 0.f, 0.f, 0.f};

  const int kend = CAUSAL ? (q0 + 64) : S_;
  for (int kk0 = 0; kk0 < kend; kk0 += 64) {
    __syncthreads();
#pragma unroll
    for (int p = 0; p < 2; ++p) {
      int e = p * 2048 + tid * 8;
      int r = e >> 6, c = e & 63;
      *(uint4*)&Ks[r * LDK + c] = *(const uint4*)(Kg + base + (long)(kk0 + r) * D_ + c);
      *(uint4*)&Vs[r * LDK + c] = *(const uint4*)(Vt + vtbase + (long)r * S_ + kk0 + c);
    }
    __syncthreads();

    f32x4_t s[4];
#pragma unroll
    for (int nb = 0; nb < 4; ++nb) {
      f32x4_t a = (f32x4_t){0.f, 0.f, 0.f, 0.f};
#pragma unroll
      for (int ks = 0; ks < 2; ++ks) {
        bf16x8_t kf = *(const bf16x8_t*)&Ks[(nb * 16 + l15) * LDK + ks * 32 + quad * 8];
        a = __builtin_amdgcn_mfma_f32_16x16x32_bf16(qf[ks], kf, a, 0, 0, 0);
      }
      s[nb] = a;
    }

#pragma unroll
    for (int r = 0; r < 4; ++r) {
      float mx = -1e30f;
#pragma unroll
      for (int nb = 0; nb < 4; ++nb) {
        float v = s[nb][r] * 0.125f;  // 1/sqrt(64)
        if (CAUSAL) {
          int kc = kk0 + nb * 16 + l15;
          int qr = q0 + wave * 16 + quad * 4 + r;
          if (kc > qr) v = -1e30f;
        }
        s[nb][r] = v;
        mx = fmaxf(mx, v);
      }
      mx = fmaxf(mx, __shfl_xor(mx, 1));
      mx = fmaxf(mx, __shfl_xor(mx, 2));
      mx = fmaxf(mx, __shfl_xor(mx, 4));
      mx = fmaxf(mx, __shfl_xor(mx, 8));
      const float mnew = fmaxf(mi[r], mx);
      float sum = 0.f;
#pragma unroll
      for (int nb = 0; nb < 4; ++nb) {
        float p = __expf(s[nb][r] - mnew);
        s[nb][r] = p;
        sum += p;
      }
      sum += __shfl_xor(sum, 1);
      sum += __shfl_xor(sum, 2);
      sum += __shfl_xor(sum, 4);
      sum += __shfl_xor(sum, 8);
      const float alpha = __expf(mi[r] - mnew);
      li[r] = li[r] * alpha + sum;
      mi[r] = mnew;
#pragma unroll
      for (int d = 0; d < 4; ++d) o[d][r] *= alpha;
    }

    bf16_t* Pw = &Ps[wave][0];
#pragma unroll
    for (int r = 0; r < 4; ++r)
#pragma unroll
      for (int nb = 0; nb < 4; ++nb)
        Pw[(quad * 4 + r) * LDK + nb * 16 + l15] = (bf16_t)s[nb][r];

#pragma unroll
    for (int ks = 0; ks < 2; ++ks) {
      bf16x8_t pf = *(const bf16x8_t*)&Pw[l15 * LDK + ks * 32 + quad * 8];
#pragma unroll
      for (int d = 0; d < 4; ++d) {
        bf16x8_t vf = *(const bf16x8_t*)&Vs[(d * 16 + l15) * LDK + ks * 32 + quad * 8];
        o[d] = __builtin_amdgcn_mfma_f32_16x16x32_bf16(pf, vf, o[d], 0, 0, 0);
      }
    }
  }

#pragma unroll
  for (int d = 0; d < 4; ++d) {
#pragma unroll
    for (int r = 0; r < 4; ++r) {
      const long row = q0 + wave * 16 + quad * 4 + r;
      O[base + row * (long)D_ + d * 16 + l15] = (bf16_t)(o[d][r] / li[r]);
    }
  }
}

// ---------------------------------------------------------------------------
extern "C" void kernel_launch(void* const* d_in, const int* in_sizes, int n_in,
                              void* d_out, int out_size, void* d_ws, size_t ws_size,
                              hipStream_t stream) {
  const float* x    = (const float*)d_in[0];
  const float* enc  = (const float*)d_in[1];
  const float* saWq = (const float*)d_in[4];  const float* sabq = (const float*)d_in[5];
  const float* saWk = (const float*)d_in[6];  const float* sabk = (const float*)d_in[7];
  const float* saWv = (const float*)d_in[8];  const float* sabv = (const float*)d_in[9];
  const float* saWo = (const float*)d_in[10]; const float* sabo = (const float*)d_in[11];
  const float* caWq = (const float*)d_in[12]; const float* cabq = (const float*)d_in[13];
  const float* caWk = (const float*)d_in[14]; const float* cabk = (const float*)d_in[15];
  const float* caWv = (const float*)d_in[16]; const float* cabv = (const float*)d_in[17];
  const float* caWo = (const float*)d_in[18]; const float* cabo = (const float*)d_in[19];
  const float* ffW1 = (const float*)d_in[20]; const float* ffb1 = (const float*)d_in[21];
  const float* ffW2 = (const float*)d_in[22]; const float* ffb2 = (const float*)d_in[23];
  const float* ln0a = (const float*)d_in[24]; const float* ln0b = (const float*)d_in[25];
  const float* ln1a = (const float*)d_in[26]; const float* ln1b = (const float*)d_in[27];
  const float* ln2a = (const float*)d_in[28]; const float* ln2b = (const float*)d_in[29];

  char* ws = (char*)d_ws;
  size_t off = 0;
  auto alloc = [&](size_t bytes) -> void* {
    void* p = ws + off;
    off += (bytes + 255) & ~(size_t)255;
    return p;
  };
  bf16_t* wt_saq = (bf16_t*)alloc(512 * 512 * 2);
  bf16_t* wt_sak = (bf16_t*)alloc(512 * 512 * 2);
  bf16_t* wt_sav = (bf16_t*)alloc(512 * 512 * 2);
  bf16_t* wt_sao = (bf16_t*)alloc(512 * 512 * 2);
  bf16_t* wt_caq = (bf16_t*)alloc(512 * 512 * 2);
  bf16_t* wt_cak = (bf16_t*)alloc(512 * 512 * 2);
  bf16_t* wt_cav = (bf16_t*)alloc(512 * 512 * 2);
  bf16_t* wt_cao = (bf16_t*)alloc(512 * 512 * 2);
  bf16_t* wt_f1  = (bf16_t*)alloc((size_t)512 * 2048 * 2);
  bf16_t* wt_f2  = (bf16_t*)alloc((size_t)2048 * 512 * 2);
  bf16_t* enc_b  = (bf16_t*)alloc((size_t)M_ * D_ * 2);
  bf16_t* nbuf   = (bf16_t*)alloc((size_t)M_ * D_ * 2);
  bf16_t* qb     = (bf16_t*)alloc((size_t)M_ * D_ * 2);
  bf16_t* kb     = (bf16_t*)alloc((size_t)M_ * D_ * 2);
  bf16_t* vb     = (bf16_t*)alloc((size_t)M_ * D_ * 2);
  bf16_t* vtb    = (bf16_t*)alloc((size_t)M_ * D_ * 2);
  bf16_t* attnb  = (bf16_t*)alloc((size_t)M_ * D_ * 2);
  bf16_t* hid    = (bf16_t*)alloc((size_t)M_ * DFF_ * 2);
  float*  x1     = (float*)alloc((size_t)M_ * D_ * 4);
  float*  x2     = (float*)alloc((size_t)M_ * D_ * 4);

  // Weight prep (same every call; graph-safe).
  wtrans<<<dim3(8, 8), 256, 0, stream>>>(saWq, wt_saq, 512, 512);
  wtrans<<<dim3(8, 8), 256, 0, stream>>>(saWk, wt_sak, 512, 512);
  wtrans<<<dim3(8, 8), 256, 0, stream>>>(saWv, wt_sav, 512, 512);
  wtrans<<<dim3(8, 8), 256, 0, stream>>>(saWo, wt_sao, 512, 512);
  wtrans<<<dim3(8, 8), 256, 0, stream>>>(caWq, wt_caq, 512, 512);
  wtrans<<<dim3(8, 8), 256, 0, stream>>>(caWk, wt_cak, 512, 512);
  wtrans<<<dim3(8, 8), 256, 0, stream>>>(caWv, wt_cav, 512, 512);
  wtrans<<<dim3(8, 8), 256, 0, stream>>>(caWo, wt_cao, 512, 512);
  wtrans<<<dim3(8, 32), 256, 0, stream>>>(ffW1, wt_f1, 512, 2048);
  wtrans<<<dim3(32, 8), 256, 0, stream>>>(ffW2, wt_f2, 2048, 512);
  cvt_bf16<<<1024, 256, 0, stream>>>(enc, enc_b);

  // Residual 0: self-attention
  ln_kernel<<<1024, 256, 0, stream>>>(x, ln0a, ln0b, nbuf);
  {
    GArg z0{nbuf, wt_saq, sabq, nullptr, qb};
    GArg z1{nbuf, wt_sak, sabk, nullptr, kb};
    GArg z2{nbuf, wt_sav, sabv, nullptr, vb};
    gemm_bt<128, 0><<<dim3(32, 4, 3), 256, 0, stream>>>(z0, z1, z2, M_, 512, 512);
  }
  vtrans<<<dim3(32, 16), 256, 0, stream>>>(vb, vtb);
  flash_attn<true><<<dim3(32, 16), 256, 0, stream>>>(qb, kb, vtb, attnb);
  {
    GArg o1{attnb, wt_sao, sabo, x, x1};
    gemm_bt<64, 2><<<dim3(32, 8, 1), 256, 0, stream>>>(o1, o1, o1, M_, 512, 512);
  }

  // Residual 1: cross-attention (K,V from raw encoder_output)
  ln_kernel<<<1024, 256, 0, stream>>>(x1, ln1a, ln1b, nbuf);
  {
    GArg c0{nbuf,  wt_caq, cabq, nullptr, qb};
    GArg c1{enc_b, wt_cak, cabk, nullptr, kb};
    GArg c2{enc_b, wt_cav, cabv, nullptr, vb};
    gemm_bt<128, 0><<<dim3(32, 4, 3), 256, 0, stream>>>(c0, c1, c2, M_, 512, 512);
  }
  vtrans<<<dim3(32, 16), 256, 0, stream>>>(vb, vtb);
  flash_attn<false><<<dim3(32, 16), 256, 0, stream>>>(qb, kb, vtb, attnb);
  {
    GArg o2{attnb, wt_cao, cabo, x1, x2};
    gemm_bt<64, 2><<<dim3(32, 8, 1), 256, 0, stream>>>(o2, o2, o2, M_, 512, 512);
  }

  // Residual 2: FFN
  ln_kernel<<<1024, 256, 0, stream>>>(x2, ln2a, ln2b, nbuf);
  {
    GArg f1{nbuf, wt_f1, ffb1, nullptr, hid};
    gemm_bt<128, 1><<<dim3(32, 16, 1), 256, 0, stream>>>(f1, f1, f1, M_, DFF_, 512);
  }
  {
    GArg f2{hid, wt_f2, ffb2, x2, d_out};
    gemm_bt<64, 2><<<dim3(32, 8, 1), 256, 0, stream>>>(f2, f2, f2, M_, 512, DFF_);
  }
}